// Round 1
// baseline (189.760 us; speedup 1.0000x reference)
//
#include <hip/hip_runtime.h>
#include <hip/hip_bf16.h>
#include <math.h>

#define M_  4
#define B_  2048
#define K_  32
#define D_  256
#define DZ_ 128
#define PAD 68

// ---------------------------------------------------------------------------
// K0: Wqk[m][z][d] = sum_e W_Q[z][e] * W_K[m][d][e]   (fold W_Q into W_K)
// grid: M_*DZ_ blocks, 256 threads (thread = d)
// ---------------------------------------------------------------------------
__global__ void __launch_bounds__(256) k0_wqk(const float* __restrict__ W_Q,
                                              const float* __restrict__ W_K,
                                              float* __restrict__ Wqk) {
    int mz = blockIdx.x;
    int m = mz >> 7, z = mz & 127;
    int d = threadIdx.x;
    __shared__ float wq[D_];
    wq[d] = W_Q[z * D_ + d];
    __syncthreads();
    const float* wk = W_K + (m * D_ + d) * D_;
    float acc = 0.f;
#pragma unroll 8
    for (int e = 0; e < D_; ++e) acc = fmaf(wq[e], wk[e], acc);
    Wqk[(m * DZ_ + z) * D_ + d] = acc;
}

// ---------------------------------------------------------------------------
// K1: Qk[m][b][d] = sum_z z_anc[b][z] * Wqk[m][z][d]
// tiled fp32 GEMM [2048x128]@[128x256] per m; 64x64 tiles, 256 thr, 4x4/thread
// ---------------------------------------------------------------------------
__global__ void __launch_bounds__(256) k1_qk(const float* __restrict__ z_anc,
                                             const float* __restrict__ Wqk,
                                             float* __restrict__ Qk) {
    int m = blockIdx.z;
    int b0 = blockIdx.x * 64, d0 = blockIdx.y * 64;
    int t = threadIdx.x, tx = t & 15, ty = t >> 4;
    __shared__ float As[64 * PAD];  // [bi][kk]
    __shared__ float Bs[64 * PAD];  // [kk][dj]
    float c[4][4] = {};
    for (int kc = 0; kc < DZ_; kc += 64) {
#pragma unroll
        for (int it = 0; it < 4; ++it) {
            int s = it * 256 + t, bi = s >> 4, k4 = (s & 15) * 4;
            *(float4*)&As[bi * PAD + k4] =
                *(const float4*)&z_anc[(b0 + bi) * DZ_ + kc + k4];
        }
#pragma unroll
        for (int it = 0; it < 4; ++it) {
            int s = it * 256 + t, kk = s >> 4, d4 = (s & 15) * 4;
            *(float4*)&Bs[kk * PAD + d4] =
                *(const float4*)&Wqk[(m * DZ_ + kc + kk) * D_ + d0 + d4];
        }
        __syncthreads();
#pragma unroll 4
        for (int kk = 0; kk < 64; ++kk) {
            float a[4];
#pragma unroll
            for (int i = 0; i < 4; ++i) a[i] = As[(ty * 4 + i) * PAD + kk];
            float4 b4 = *(const float4*)&Bs[kk * PAD + tx * 4];
#pragma unroll
            for (int i = 0; i < 4; ++i) {
                c[i][0] = fmaf(a[i], b4.x, c[i][0]);
                c[i][1] = fmaf(a[i], b4.y, c[i][1]);
                c[i][2] = fmaf(a[i], b4.z, c[i][2]);
                c[i][3] = fmaf(a[i], b4.w, c[i][3]);
            }
        }
        __syncthreads();
    }
#pragma unroll
    for (int i = 0; i < 4; ++i) {
        float4 v = make_float4(c[i][0], c[i][1], c[i][2], c[i][3]);
        *(float4*)&Qk[(m * B_ + b0 + ty * 4 + i) * D_ + d0 + tx * 4] = v;
    }
}

// ---------------------------------------------------------------------------
// K2: per-b main pass. For each m:
//   scores[k] = h_nei[m,b,k,:].Qk[m,b,:]/16 + log(ew+eps) + lw, mask, softmax
//   hbar'[m,b,:] = vw[m] * sum_k attn[k]*h_nei[m,b,k,:]           -> ws
//   out[b,:]    += vw[m] * sum_k attn[k]*lbl_delta[b,k,m,:]       -> d_out
// 2048 blocks x 256 threads; h tile (32KB) staged in LDS during score pass.
// ---------------------------------------------------------------------------
__global__ void __launch_bounds__(256) k2_main(
    const float* __restrict__ h_nei, const float* __restrict__ ew_anc,
    const float* __restrict__ vmask, const float* __restrict__ lbl_delta,
    const float* __restrict__ lbl_w, const float* __restrict__ Qk,
    const float* __restrict__ log_vw,
    float* __restrict__ hbar, float* __restrict__ out)
{
    int b = blockIdx.x;
    int t = threadIdx.x;
    int w = t >> 6, l = t & 63;
    __shared__ float hs[K_ * D_];          // 32 KB
    __shared__ float sc[K_], adj[K_], at[K_];

    // vw = softmax(log_vw), 4 elems, computed redundantly per thread (uniform)
    float lv[4] = {log_vw[0], log_vw[1], log_vw[2], log_vw[3]};
    float mv = fmaxf(fmaxf(lv[0], lv[1]), fmaxf(lv[2], lv[3]));
    float ex[4], den = 0.f;
#pragma unroll
    for (int i = 0; i < 4; ++i) { ex[i] = expf(lv[i] - mv); den += ex[i]; }
    float vw[4];
#pragma unroll
    for (int i = 0; i < 4; ++i) vw[i] = ex[i] / den;

    float acc_ld = 0.f;
    for (int m = 0; m < M_; ++m) {
        __syncthreads();  // protect hs/sc/adj/at reuse across m iterations
        const float* hb = h_nei + (m * B_ + b) * (K_ * D_);
        float4 q4 = *(const float4*)&Qk[(m * B_ + b) * D_ + 4 * l];
        // stream h tile: slot s = i*256+t -> row k = i*4+w, float4 col l
        float accs[8];
#pragma unroll
        for (int i = 0; i < 8; ++i) {
            int s = i * 256 + t;
            float4 h4 = *(const float4*)&hb[4 * s];
            *(float4*)&hs[4 * s] = h4;
            accs[i] = h4.x * q4.x + h4.y * q4.y + h4.z * q4.z + h4.w * q4.w;
        }
        // wave-reduce each partial: wave w, iter i owns k = i*4+w
#pragma unroll
        for (int i = 0; i < 8; ++i) {
            float v = accs[i];
            v += __shfl_xor(v, 32); v += __shfl_xor(v, 16); v += __shfl_xor(v, 8);
            v += __shfl_xor(v, 4);  v += __shfl_xor(v, 2);  v += __shfl_xor(v, 1);
            if (l == 0) sc[i * 4 + w] = v;
        }
        __syncthreads();
        if (t < K_) {
            int idx = (b * K_ + t) * M_ + m;
            float s = sc[t] * 0.0625f + logf(ew_anc[idx] + 1e-6f) + lbl_w[idx];
            if (vmask[idx] == 0.f) s = -1e9f;
            adj[t] = s;
        }
        __syncthreads();
        // softmax over 32 (redundant per-thread, LDS broadcast reads are free)
        float mx = -3.4e38f;
        for (int k = 0; k < K_; ++k) mx = fmaxf(mx, adj[k]);
        float dsum = 0.f;
        for (int k = 0; k < K_; ++k) dsum += expf(adj[k] - mx);
        if (t < K_) at[t] = expf(adj[t] - mx) / dsum;
        __syncthreads();
        // hbar' = vw[m] * sum_k attn[k]*h[k][t]  (hs read: bank t%32, 2-way = free)
        float ah = 0.f;
#pragma unroll 8
        for (int k = 0; k < K_; ++k) ah = fmaf(at[k], hs[k * D_ + t], ah);
        hbar[(m * B_ + b) * D_ + t] = vw[m] * ah;
        // lbl_delta part: rows contiguous, thread t = column e, coalesced
        const float* ldp = lbl_delta + b * (K_ * M_ * D_) + m * D_;
        float vwm = vw[m];
#pragma unroll 8
        for (int k = 0; k < K_; ++k)
            acc_ld = fmaf(vwm * at[k], ldp[k * (M_ * D_) + t], acc_ld);
    }
    out[b * D_ + t] = acc_ld;
}

// ---------------------------------------------------------------------------
// K3: out[b][e] += sum_d hbar'[m][b][d] * W_V[m][d][e], split-K over m
// grid (32,4,4); 64x64 tiles, K=256 per m; atomicAdd accumulation
// ---------------------------------------------------------------------------
__global__ void __launch_bounds__(256) k3_gemm(const float* __restrict__ hbar,
                                               const float* __restrict__ W_V,
                                               float* __restrict__ out) {
    int m = blockIdx.z;
    int b0 = blockIdx.x * 64, e0 = blockIdx.y * 64;
    int t = threadIdx.x, tx = t & 15, ty = t >> 4;
    __shared__ float As[64 * PAD];  // [bi][kk]
    __shared__ float Bs[64 * PAD];  // [kk][ej]
    float c[4][4] = {};
    for (int kc = 0; kc < D_; kc += 64) {
#pragma unroll
        for (int it = 0; it < 4; ++it) {
            int s = it * 256 + t, bi = s >> 4, k4 = (s & 15) * 4;
            *(float4*)&As[bi * PAD + k4] =
                *(const float4*)&hbar[(m * B_ + b0 + bi) * D_ + kc + k4];
        }
#pragma unroll
        for (int it = 0; it < 4; ++it) {
            int s = it * 256 + t, kk = s >> 4, e4 = (s & 15) * 4;
            *(float4*)&Bs[kk * PAD + e4] =
                *(const float4*)&W_V[(m * D_ + kc + kk) * D_ + e0 + e4];
        }
        __syncthreads();
#pragma unroll 4
        for (int kk = 0; kk < 64; ++kk) {
            float a[4];
#pragma unroll
            for (int i = 0; i < 4; ++i) a[i] = As[(ty * 4 + i) * PAD + kk];
            float4 b4 = *(const float4*)&Bs[kk * PAD + tx * 4];
#pragma unroll
            for (int i = 0; i < 4; ++i) {
                c[i][0] = fmaf(a[i], b4.x, c[i][0]);
                c[i][1] = fmaf(a[i], b4.y, c[i][1]);
                c[i][2] = fmaf(a[i], b4.z, c[i][2]);
                c[i][3] = fmaf(a[i], b4.w, c[i][3]);
            }
        }
        __syncthreads();
    }
#pragma unroll
    for (int i = 0; i < 4; ++i)
#pragma unroll
        for (int j = 0; j < 4; ++j)
            atomicAdd(&out[(b0 + ty * 4 + i) * D_ + e0 + tx * 4 + j], c[i][j]);
}

// ---------------------------------------------------------------------------
extern "C" void kernel_launch(void* const* d_in, const int* in_sizes, int n_in,
                              void* d_out, int out_size, void* d_ws, size_t ws_size,
                              hipStream_t stream) {
    const float* h_nei     = (const float*)d_in[0];
    const float* ew_anc    = (const float*)d_in[1];
    const float* vmask     = (const float*)d_in[2];
    const float* z_anc     = (const float*)d_in[3];
    const float* lbl_delta = (const float*)d_in[4];
    const float* lbl_w     = (const float*)d_in[5];
    const float* W_Q       = (const float*)d_in[6];
    const float* W_K       = (const float*)d_in[7];
    const float* W_V       = (const float*)d_in[8];
    const float* log_vw    = (const float*)d_in[9];
    float* out = (float*)d_out;

    // ws layout (floats): Wqk[4*128*256] | Qk[4*2048*256] | hbar[4*2048*256]
    float* ws   = (float*)d_ws;
    float* Wqk  = ws;
    float* Qk   = ws + (M_ * DZ_ * D_);
    float* hbar = ws + (M_ * DZ_ * D_) + (M_ * B_ * D_);

    k0_wqk<<<M_ * DZ_, 256, 0, stream>>>(W_Q, W_K, Wqk);

    dim3 g1(B_ / 64, D_ / 64, M_);
    k1_qk<<<g1, 256, 0, stream>>>(z_anc, Wqk, Qk);

    k2_main<<<B_, 256, 0, stream>>>(h_nei, ew_anc, vmask, lbl_delta, lbl_w,
                                    Qk, log_vw, hbar, out);

    dim3 g3(B_ / 64, D_ / 64, M_);
    k3_gemm<<<g3, 256, 0, stream>>>(hbar, W_V, out);
}